// Round 6
// baseline (207.524 us; speedup 1.0000x reference)
//
#include <hip/hip_runtime.h>

// AtlasAttention v4 — K-folded, fused MLP1+MLP2 with split-K atomics.
// out = MLP2(relu(MLP1(poly(clip(X@Wq)))))[:, :64], heads folded.
// Structure:
//   setup: cast X->bf16, transpose Wq/W1[64:]/W2[:, :64] to [n][k] bf16,
//          b1' = b1 + c0*colsum(W1[:64])   (constant poly feature folded out)
//   gemm1: Qb = bf16(Xb @ Wqb^T)            (m97-style, 64x128 tile)
//   out_init: out[row][col] = b2[col]
//   fused: per block (128 rows x 128 h-cols): stage q-tile+W1-slice in LDS once,
//          barrier-free K=192 loop with poly-in-registers -> H-tile,
//          H-tile -> LDS (wave-private) -> x W2-slice -> atomicAdd out partials.
//          H never touches global memory. grid.y=4 is split-K of the 2nd GEMM.
// Clamp(+-1e6) elided: |x|<=10 and coeffs=1/i! => |c3 x^3| <= 167 << 1e6 (never binds).
//
// ws layout (bytes):
//   Xb  @ 0          : 8192*768*2  = 12,582,912
//   Wqb @ 12,582,912 : 768*768*2   =  1,179,648   [n][k]
//   W1t @ 13,762,560 : 512*192*2   =    196,608   [n][k], k = feature-64 (oct 1..3)
//   W2t @ 13,959,168 : 64*512*2    =     65,536   [n][k], first 64 cols of W2
//   b1p @ 14,024,704 : 512*4       =      2,048
//   Qb  @ 14,026,752 : 98304*64*2  = 12,582,912

typedef unsigned short u16;
typedef __attribute__((ext_vector_type(8))) short short8;
typedef __attribute__((ext_vector_type(4))) float f32x4;
typedef __attribute__((ext_vector_type(4))) u16 u16x4;

__device__ __forceinline__ u16 f2bf(float f) {
    unsigned u = __builtin_bit_cast(unsigned, f);
    u += 0x7FFFu + ((u >> 16) & 1u);   // RNE
    return (u16)(u >> 16);
}
__device__ __forceinline__ float bf2f(u16 h) {
    return __builtin_bit_cast(float, (unsigned)h << 16);
}
__device__ __forceinline__ void gl2lds16(const void* g, void* l) {
    __builtin_amdgcn_global_load_lds(
        (const __attribute__((address_space(1))) unsigned int*)g,
        (__attribute__((address_space(3))) unsigned int*)l, 16, 0, 0);
}

// ---------------- setup kernels ----------------

__global__ __launch_bounds__(256) void cast_f32_bf16(const float* __restrict__ in,
                                                     u16* __restrict__ out, int n4) {
    int i = blockIdx.x * 256 + threadIdx.x;
    if (i < n4) {
        float4 v = reinterpret_cast<const float4*>(in)[i];
        u16x4 o = {f2bf(v.x), f2bf(v.y), f2bf(v.z), f2bf(v.w)};
        reinterpret_cast<u16x4*>(out)[i] = o;
    }
}

// in: [R][Cin] fp32; out: [C][R] bf16. grid (C/32, R/32), block (32,8).
__global__ __launch_bounds__(256) void transpose_cast(const float* __restrict__ in,
                                                      u16* __restrict__ out,
                                                      int R, int Cin) {
    __shared__ float t[32][33];
    const int c0 = blockIdx.x * 32, r0 = blockIdx.y * 32;
    const int tx = threadIdx.x, ty = threadIdx.y;
    #pragma unroll
    for (int j = 0; j < 32; j += 8)
        t[ty + j][tx] = in[(size_t)(r0 + ty + j) * Cin + c0 + tx];
    __syncthreads();
    #pragma unroll
    for (int j = 0; j < 32; j += 8)
        out[(size_t)(c0 + ty + j) * R + r0 + tx] = f2bf(t[tx][ty + j]);
}

// b1p[n] = b1[n] + c0 * sum_{d<64} W1[d][n].  grid 2 x 256.
__global__ __launch_bounds__(256) void b1fold(const float* __restrict__ W1,
                                              const float* __restrict__ b1,
                                              const float* __restrict__ coeffs,
                                              float* __restrict__ b1p) {
    int n = blockIdx.x * 256 + threadIdx.x;
    float s = 0.f;
    #pragma unroll 8
    for (int d = 0; d < 64; ++d) s += W1[d * 512 + n];
    b1p[n] = b1[n] + coeffs[0] * s;
}

// out[row][col] = b2[col]  (bias pre-load for the atomic split-K). grid 6144 x 256.
__global__ __launch_bounds__(256) void out_init(const float* __restrict__ b2,
                                                float* __restrict__ out) {
    long i = (long)blockIdx.x * 256 + threadIdx.x;   // < 98304*16
    const float4 v = *reinterpret_cast<const float4*>(b2 + (i & 15) * 4);
    reinterpret_cast<float4*>(out)[i] = v;
}

// ---------------- GEMM1: Qb = bf16(Xb @ Wqb^T), m97-style ----------------
// BM=64 BN=128, 4 waves of 32x64 tiles, grid (128, 6).

__global__ __launch_bounds__(256)
void gemm1(const u16* __restrict__ A, const u16* __restrict__ B,
           u16* __restrict__ C)
{
    constexpr int BM = 64, BN = 128, K = 768, LD = 768;
    __shared__ u16 As[BM * 32];
    __shared__ u16 Bs[BN * 32];

    const int tid = threadIdx.x;
    const int w = tid >> 6, lane = tid & 63;
    const int lrow = lane >> 2, lslot = lane & 3;
    const int m16 = lane & 15, quad = lane >> 4;
    const int bm = blockIdx.x * BM, bn = blockIdx.y * BN;
    const int wr = (w & 1) * 32, wc = (w >> 1) * 64;

    f32x4 acc[2][4];
    #pragma unroll
    for (int i = 0; i < 2; ++i)
        #pragma unroll
        for (int j = 0; j < 4; ++j)
            acc[i][j] = (f32x4){0.f, 0.f, 0.f, 0.f};

    for (int k0 = 0; k0 < K; k0 += 32) {
        #pragma unroll
        for (int i = 0; i < 2; ++i) {
            const int row = (w * 2 + i) * 16 + lrow;
            const int c = lslot ^ ((row >> 2) & 3);
            gl2lds16(B + (size_t)(bn + row) * LD + k0 + c * 8,
                     &Bs[row * 32 + lslot * 8]);
        }
        {
            const int row = w * 16 + lrow;
            const int c = lslot ^ ((row >> 2) & 3);
            gl2lds16(A + (size_t)(bm + row) * LD + k0 + c * 8,
                     &As[row * 32 + lslot * 8]);
        }
        __syncthreads();

        short8 af[2], bfr[4];
        #pragma unroll
        for (int i = 0; i < 2; ++i) {
            const int r = wr + i * 16 + m16;
            const int s = quad ^ ((r >> 2) & 3);
            af[i] = *reinterpret_cast<const short8*>(&As[r * 32 + s * 8]);
        }
        #pragma unroll
        for (int j = 0; j < 4; ++j) {
            const int r = wc + j * 16 + m16;
            const int s = quad ^ ((r >> 2) & 3);
            bfr[j] = *reinterpret_cast<const short8*>(&Bs[r * 32 + s * 8]);
        }
        #pragma unroll
        for (int i = 0; i < 2; ++i)
            #pragma unroll
            for (int j = 0; j < 4; ++j)
                acc[i][j] = __builtin_amdgcn_mfma_f32_16x16x32_bf16(
                    af[i], bfr[j], acc[i][j], 0, 0, 0);
        __syncthreads();
    }

    #pragma unroll
    for (int j = 0; j < 4; ++j) {
        const int col = bn + wc + j * 16 + m16;
        #pragma unroll
        for (int i = 0; i < 2; ++i)
            #pragma unroll
            for (int r = 0; r < 4; ++r) {
                const int row = bm + wr + i * 16 + quad * 4 + r;
                C[(size_t)row * LD + col] = f2bf(acc[i][j][r]);
            }
    }
}

// ---------------- fused MLP (K-folded, split-K atomics) ----------------
// grid (768, 4). Block: 128 q-rows x 128 h-cols. 4 waves; wave = 32 rows.
// LDS 64 KB total: Qs [128][64] bf16 swizzled (16 KB) + Ws [128][192] bf16
// swizzled (48 KB); after barrier2 the Ws region is reused as wave-private
// Hs [32][128] bf16 (8 KB per wave).
// Swizzle rule everywhere: 8-elem chunk c of row r stored at slot c^(r&7)
// within r's row (XOR stays inside an 8-aligned chunk block) -> all
// ds_read_b128 / write patterns are <=2-way bank aliased (free).

__global__ __launch_bounds__(256, 2)
void fused_mlp(const u16* __restrict__ Qb,      // [98304][64] bf16
               const u16* __restrict__ W1t,     // [512][192] bf16
               const float* __restrict__ b1p,   // [512]
               const u16* __restrict__ W2t,     // [64][512] bf16
               const float* __restrict__ coeffs,
               float* __restrict__ out)         // [98304][64] fp32, pre-init b2
{
    __shared__ u16 lds[32768];                  // 64 KB
    u16* Qs = lds;                              // 8192 elems
    u16* Ws = lds + 8192;                       // 24576 elems

    const int tid = threadIdx.x;
    const int w = tid >> 6, lane = tid & 63;
    const int m16 = lane & 15, quad = lane >> 4;
    const long bm = (long)blockIdx.x * 128;
    const int bn = blockIdx.y * 128;            // h-col / gemm3-k slice
    const float c1 = coeffs[1], c2 = coeffs[2], c3 = coeffs[3];

    // ---- stage Qs: wave w stages its own rows w*32..w*32+31 (gl2lds 16B) ----
    #pragma unroll
    for (int i = 0; i < 4; ++i) {
        const int s = (w * 4 + i) * 64 + lane;  // lane-linear LDS slots
        const int r = s >> 3, sc = s & 7;
        const int c = sc ^ (r & 7);
        gl2lds16(Qb + (bm + r) * 64 + c * 8, &Qs[r * 64 + sc * 8]);
    }
    // ---- stage Ws cooperatively: thread = (row n, half), 12 chunks each ----
    {
        const int n = tid >> 1, half = tid & 1;
        const u16* src = W1t + (size_t)(bn + n) * 192;
        #pragma unroll
        for (int j = 0; j < 12; ++j) {
            const int c = half * 12 + j;
            const short8 v = *reinterpret_cast<const short8*>(src + c * 8);
            *reinterpret_cast<short8*>(&Ws[n * 192 + (c ^ (n & 7)) * 8]) = v;
        }
    }
    __syncthreads();   // barrier 1 (drains gl2lds too)

    // ---- stage 1: H-tile = poly(q) @ W1slice^T, K=192, no barriers ----
    f32x4 acc1[2][8];
    #pragma unroll
    for (int i = 0; i < 2; ++i)
        #pragma unroll
        for (int j = 0; j < 8; ++j)
            acc1[i][j] = (f32x4){0.f, 0.f, 0.f, 0.f};

    #pragma unroll
    for (int ks = 0; ks < 6; ++ks) {
        const int k0 = ks * 32;
        const int kq = k0 + quad * 8;           // reduced-k of this fragment
        const int d0 = kq & 63;                 // q dim
        const int oct = 1 + (kq >> 6);          // power (1..3), per-lane scalar
        const float coef = (oct == 1) ? c1 : (oct == 2) ? c2 : c3;

        short8 af[2];
        #pragma unroll
        for (int i = 0; i < 2; ++i) {
            const int row = w * 32 + i * 16 + m16;
            const int slot = (d0 >> 3) ^ (row & 7);
            const short8 qv = *reinterpret_cast<const short8*>(&Qs[row * 64 + slot * 8]);
            short8 pv;
            #pragma unroll
            for (int e = 0; e < 8; ++e) {
                float x = bf2f((u16)qv[e]);
                x = fminf(fmaxf(x, -10.f), 10.f);
                const float x2 = x * x;
                const float t = (oct == 1) ? x : (oct == 2) ? x2 : x2 * x;
                pv[e] = (short)f2bf(coef * t);
            }
            af[i] = pv;
        }
        short8 bfr[8];
        #pragma unroll
        for (int j = 0; j < 8; ++j) {
            const int n = j * 16 + m16;
            const int slot = ((k0 >> 3) + quad) ^ (n & 7);
            bfr[j] = *reinterpret_cast<const short8*>(&Ws[n * 192 + slot * 8]);
        }
        #pragma unroll
        for (int i = 0; i < 2; ++i)
            #pragma unroll
            for (int j = 0; j < 8; ++j)
                acc1[i][j] = __builtin_amdgcn_mfma_f32_16x16x32_bf16(
                    af[i], bfr[j], acc1[i][j], 0, 0, 0);
    }
    __syncthreads();   // barrier 2: everyone done with Ws -> reuse as Hs

    // ---- bias+relu, H-tile -> wave-private Hs [32][128] swizzled ----
    u16* Hsw = lds + 8192 + w * 4096;
    #pragma unroll
    for (int j = 0; j < 8; ++j) {
        const int nl = j * 16 + m16;
        const float bv = b1p[bn + nl];
        #pragma unroll
        for (int i = 0; i < 2; ++i) {
            #pragma unroll
            for (int r = 0; r < 4; ++r) {
                const int rl = i * 16 + quad * 4 + r;
                const float v = fmaxf(acc1[i][j][r] + bv, 0.f);
                const int slot = (nl >> 3) ^ (rl & 7);
                Hsw[rl * 128 + slot * 8 + (nl & 7)] = f2bf(v);
            }
        }
    }
    // wave-private: no barrier needed (same-wave ds ordering via lgkmcnt)

    // ---- stage 2: out-partial[32][64] = H-tile @ W2slice^T (K=128 local) ----
    f32x4 acc2[2][4];
    #pragma unroll
    for (int i = 0; i < 2; ++i)
        #pragma unroll
        for (int j = 0; j < 4; ++j)
            acc2[i][j] = (f32x4){0.f, 0.f, 0.f, 0.f};

    #pragma unroll
    for (int kk = 0; kk < 4; ++kk) {
        short8 af2[2];
        #pragma unroll
        for (int ii = 0; ii < 2; ++ii) {
            const int m = ii * 16 + m16;
            const int slot = (kk * 4 + quad) ^ (m & 7);
            af2[ii] = *reinterpret_cast<const short8*>(&Hsw[m * 128 + slot * 8]);
        }
        #pragma unroll
        for (int jj = 0; jj < 4; ++jj) {
            const short8 bf2v = *reinterpret_cast<const short8*>(
                W2t + (size_t)(jj * 16 + m16) * 512 + bn + kk * 32 + quad * 8);
            #pragma unroll
            for (int ii = 0; ii < 2; ++ii)
                acc2[ii][jj] = __builtin_amdgcn_mfma_f32_16x16x32_bf16(
                    af2[ii], bf2v, acc2[ii][jj], 0, 0, 0);
        }
    }

    // ---- atomic split-K accumulate into out (pre-initialized with b2) ----
    #pragma unroll
    for (int ii = 0; ii < 2; ++ii)
        #pragma unroll
        for (int jj = 0; jj < 4; ++jj)
            #pragma unroll
            for (int r = 0; r < 4; ++r) {
                const long row = bm + w * 32 + ii * 16 + quad * 4 + r;
                atomicAdd(&out[row * 64 + jj * 16 + m16], acc2[ii][jj][r]);
            }
}

// ---------------- host ----------------

extern "C" void kernel_launch(void* const* d_in, const int* in_sizes, int n_in,
                              void* d_out, int out_size, void* d_ws, size_t ws_size,
                              hipStream_t stream) {
    const float* X      = (const float*)d_in[0];
    const float* Wq     = (const float*)d_in[1];
    const float* coeffs = (const float*)d_in[2];
    const float* W1     = (const float*)d_in[3];
    const float* b1     = (const float*)d_in[4];
    const float* W2     = (const float*)d_in[5];
    const float* b2     = (const float*)d_in[6];
    float* out = (float*)d_out;

    char* ws = (char*)d_ws;
    u16*   Xb  = (u16*)(ws);
    u16*   Wqb = (u16*)(ws + 12582912);
    u16*   W1t = (u16*)(ws + 13762560);
    u16*   W2t = (u16*)(ws + 13959168);
    float* b1p = (float*)(ws + 14024704);
    u16*   Qb  = (u16*)(ws + 14026752);

    cast_f32_bf16<<<6144, 256, 0, stream>>>(X, Xb, 8192 * 768 / 4);
    transpose_cast<<<dim3(24, 24), dim3(32, 8), 0, stream>>>(Wq, Wqb, 768, 768);
    // W1 rows 64..255 (oct 1..3) -> W1t [512][192]
    transpose_cast<<<dim3(16, 6),  dim3(32, 8), 0, stream>>>(W1 + 64 * 512, W1t, 192, 512);
    // W2 first 64 cols -> W2t [64][512]
    transpose_cast<<<dim3(2, 16),  dim3(32, 8), 0, stream>>>(W2, W2t, 512, 256);
    b1fold<<<2, 256, 0, stream>>>(W1, b1, coeffs, b1p);

    gemm1<<<dim3(128, 6), 256, 0, stream>>>(Xb, Wqb, Qb);
    out_init<<<6144, 256, 0, stream>>>(b2, out);
    fused_mlp<<<dim3(768, 4), 256, 0, stream>>>(Qb, W1t, b1p, W2t, coeffs, out);
}